// Round 4
// baseline (61.670 us; speedup 1.0000x reference)
//
#include <hip/hip_runtime.h>
#include <hip/hip_bf16.h>
#include <math.h>

// TopKRouter: x (16384 x 2048) f32 @ gate_w^T (2048 x 64) -> top-2 + softmax.
// Output (f32): [indices as floats (N*2)] ++ [weights (N*2)].
//
// v4: split-bf16 MFMA (3-term Ootomo, err ~1e-6) + linear global_load_lds
// staging of x (1KB contiguous per wave-instruction -> DRAM-friendly streams),
// double-buffered chunks, pre-swizzled global source + XOR'd ds_read
// (both-sides swizzle, rule #21). 4 waves/block split K; LDS reduce epilogue.

constexpr int D_DIM = 2048;
constexpr int E_DIM = 64;
constexpr int BM    = 32;               // rows per block
constexpr int BKC   = 256;              // chunk columns (f32)
constexpr int NCH   = D_DIM / BKC;      // 8 chunks
constexpr int LPAD  = 68;               // logits row stride (f32)

typedef __attribute__((ext_vector_type(8))) short s16x8;  // 8 bf16
typedef __attribute__((ext_vector_type(4))) float f32x4;  // MFMA C/D

static __device__ __forceinline__ short f2bf(float f) {
    __hip_bfloat16 h = __float2bfloat16(f);   // RNE
    return *reinterpret_cast<short*>(&h);
}
static __device__ __forceinline__ float b2f(short s) {
    union { unsigned u; float f; } x;
    x.u = ((unsigned)(unsigned short)s) << 16;
    return x.f;
}

__global__ __launch_bounds__(256, 1)
void pack_w(const float* __restrict__ w, short* __restrict__ wsb) {
    const int idx = blockIdx.x * 256 + threadIdx.x;   // 64*2048
    const int e = idx >> 11, k = idx & 2047;
    const float v = w[idx];
    const short hi = f2bf(v);
    const short lo = f2bf(v - b2f(hi));
    const int g = k >> 3, j = k & 7;
    const size_t base = (size_t)(e * 256 + g) * 16 + j;  // [e][g][hi8|lo8]
    wsb[base]     = hi;
    wsb[base + 8] = lo;
}

template <bool PACKED>
__global__ __launch_bounds__(256, 2)
void router_v4(const float* __restrict__ x,
               const float* __restrict__ w,
               const short* __restrict__ wsb,
               float* __restrict__ out,
               int nrows) {
    __shared__ alignas(16) float smem[2][BM * BKC];   // 2 x 32 KB

    const int t    = threadIdx.x;
    const int lane = t & 63;
    const int wv   = t >> 6;            // wave id -> K-slice / staging rows
    const int row0 = blockIdx.x * BM;
    const int l15  = lane & 15;
    const int k8   = lane >> 4;

    // ---- staging: wave wv stages rows [wv*8, wv*8+8); one 1KB row-chunk
    // per global_load_lds (64 lanes x 16B contiguous, source pre-swizzled).
    auto stage = [&](int b, int c) {
        #pragma unroll
        for (int rr = 0; rr < 8; ++rr) {
            const int r = wv * 8 + rr;
            const char* gsrc = (const char*)(x + (size_t)(row0 + r) * D_DIM + c * BKC);
            const int boff = (lane * 16) ^ ((r & 7) << 4);   // bijective within 128B
            __builtin_amdgcn_global_load_lds(
                (const __attribute__((address_space(1))) void*)(gsrc + boff),
                (__attribute__((address_space(3))) void*)(&smem[b][r * BKC]),
                16, 0, 0);
        }
    };

    f32x4 acc[2][4];
    #pragma unroll
    for (int mf = 0; mf < 2; ++mf)
        #pragma unroll
        for (int nf = 0; nf < 4; ++nf)
            #pragma unroll
            for (int j = 0; j < 4; ++j) acc[mf][nf][j] = 0.f;

    auto compute = [&](int b, int c) {
        const char* base = (const char*)&smem[b][0];
        #pragma unroll
        for (int s = 0; s < 2; ++s) {                 // 2 K-steps per chunk
            const int bc = wv * 256 + s * 128 + k8 * 32;   // byte col in row
            // ---- A fragments from LDS (XOR'd read), split hi/lo ----
            s16x8 ah[2], al[2];
            #pragma unroll
            for (int mf = 0; mf < 2; ++mf) {
                const int r  = mf * 16 + l15;
                const int sw = (r & 7) << 4;
                const char* rp = base + r * (BKC * 4);
                const float4 v0 = *reinterpret_cast<const float4*>(rp + ((bc) ^ sw));
                const float4 v1 = *reinterpret_cast<const float4*>(rp + ((bc + 16) ^ sw));
                const float vv[8] = {v0.x, v0.y, v0.z, v0.w, v1.x, v1.y, v1.z, v1.w};
                #pragma unroll
                for (int j = 0; j < 8; ++j) {
                    const short h = f2bf(vv[j]);
                    ah[mf][j] = h;
                    al[mf][j] = f2bf(vv[j] - b2f(h));
                }
            }
            // ---- B fragments (packed hi/lo from L2-resident wsb) ----
            s16x8 bh[4], bl[4];
            const int kk = c * BKC + wv * 64 + s * 32 + k8 * 8;
            #pragma unroll
            for (int nf = 0; nf < 4; ++nf) {
                const int e = nf * 16 + l15;
                if (PACKED) {
                    const int g = kk >> 3;
                    const short* pw = wsb + (size_t)(e * 256 + g) * 16;
                    bh[nf] = *reinterpret_cast<const s16x8*>(pw);
                    bl[nf] = *reinterpret_cast<const s16x8*>(pw + 8);
                } else {
                    const float* pw = w + (size_t)e * D_DIM + kk;
                    const float4 w0 = *reinterpret_cast<const float4*>(pw);
                    const float4 w1 = *reinterpret_cast<const float4*>(pw + 4);
                    const float wvv[8] = {w0.x, w0.y, w0.z, w0.w, w1.x, w1.y, w1.z, w1.w};
                    #pragma unroll
                    for (int j = 0; j < 8; ++j) {
                        const short h = f2bf(wvv[j]);
                        bh[nf][j] = h;
                        bl[nf][j] = f2bf(wvv[j] - b2f(h));
                    }
                }
            }
            // ---- 3-term split MFMA ----
            #pragma unroll
            for (int mf = 0; mf < 2; ++mf)
                #pragma unroll
                for (int nf = 0; nf < 4; ++nf) {
                    acc[mf][nf] = __builtin_amdgcn_mfma_f32_16x16x32_bf16(al[mf], bh[nf], acc[mf][nf], 0, 0, 0);
                    acc[mf][nf] = __builtin_amdgcn_mfma_f32_16x16x32_bf16(ah[mf], bl[nf], acc[mf][nf], 0, 0, 0);
                    acc[mf][nf] = __builtin_amdgcn_mfma_f32_16x16x32_bf16(ah[mf], bh[nf], acc[mf][nf], 0, 0, 0);
                }
        }
    };

    // ---- main loop: stage(c+1) issued before compute(c); 1 drain/chunk ----
    stage(0, 0);
    asm volatile("s_waitcnt vmcnt(0)" ::: "memory");
    __syncthreads();
    #pragma unroll 1
    for (int c = 0; c < NCH; ++c) {
        if (c + 1 < NCH) stage((c + 1) & 1, c + 1);
        compute(c & 1, c);
        asm volatile("s_waitcnt vmcnt(0)" ::: "memory");
        __syncthreads();
    }

    // ---- partials -> LDS (alias staging buffers), reduce + top-2 + softmax ----
    float* lgs = &smem[0][0];   // [4][BM][LPAD] = 34.8 KB <= 64 KB
    #pragma unroll
    for (int mf = 0; mf < 2; ++mf)
        #pragma unroll
        for (int nf = 0; nf < 4; ++nf)
            #pragma unroll
            for (int j = 0; j < 4; ++j)
                lgs[((size_t)wv * BM + mf * 16 + k8 * 4 + j) * LPAD + nf * 16 + l15] = acc[mf][nf][j];
    __syncthreads();

    {
        const int row8 = lane >> 3;
        const int seg  = lane & 7;
        const int row  = wv * 8 + row8;
        float sv[8];
        #pragma unroll
        for (int j = 0; j < 8; ++j) sv[j] = 0.f;
        #pragma unroll
        for (int p = 0; p < 4; ++p) {
            const float* rp = &lgs[((size_t)p * BM + row) * LPAD + seg * 8];
            const float4 a = *reinterpret_cast<const float4*>(rp);
            const float4 bq = *reinterpret_cast<const float4*>(rp + 4);
            sv[0] += a.x;  sv[1] += a.y;  sv[2] += a.z;  sv[3] += a.w;
            sv[4] += bq.x; sv[5] += bq.y; sv[6] += bq.z; sv[7] += bq.w;
        }
        float m1 = sv[0]; int i1 = seg * 8;
        float m2 = -INFINITY; int i2 = 0;
        #pragma unroll
        for (int j = 1; j < 8; ++j) {
            const float v = sv[j]; const int idx = seg * 8 + j;
            if (v > m1)      { m2 = m1; i2 = i1; m1 = v; i1 = idx; }
            else if (v > m2) { m2 = v;  i2 = idx; }
        }
        #pragma unroll
        for (int d = 1; d < 8; d <<= 1) {
            const float M1 = __shfl_xor(m1, d); const int I1 = __shfl_xor(i1, d);
            const float M2 = __shfl_xor(m2, d); const int I2 = __shfl_xor(i2, d);
            const bool sw = (M1 > m1) || (M1 == m1 && I1 < i1);
            const float a1 = sw ? M1 : m1; const int j1 = sw ? I1 : i1;
            const float b1 = sw ? m1 : M1; const int kx = sw ? i1 : I1;
            const float a2 = sw ? M2 : m2; const int j2 = sw ? I2 : i2;
            const bool t2 = (b1 > a2) || (b1 == a2 && kx < j2);
            m1 = a1; i1 = j1;
            m2 = t2 ? b1 : a2; i2 = t2 ? kx : j2;
        }
        if (seg == 0) {
            const float e2v = expf(m2 - m1);
            const float sm  = 1.0f + e2v;
            const long  r   = row0 + row;
            const long  off = (long)nrows * 2;
            out[2 * r + 0]       = (float)i1;
            out[2 * r + 1]       = (float)i2;
            out[off + 2 * r + 0] = 1.0f / sm;
            out[off + 2 * r + 1] = e2v / sm;
        }
    }
}

extern "C" void kernel_launch(void* const* d_in, const int* in_sizes, int n_in,
                              void* d_out, int out_size, void* d_ws, size_t ws_size,
                              hipStream_t stream) {
    const float* x = (const float*)d_in[0];
    const float* w = (const float*)d_in[1];
    float* out = (float*)d_out;
    short* wsb = (short*)d_ws;
    const int nrows = in_sizes[0] / D_DIM;            // 16384
    const int grid  = nrows / BM;                     // 512
    const bool packed = ws_size >= (size_t)(E_DIM * D_DIM) * 2 * sizeof(short);

    if (packed) {
        hipLaunchKernelGGL(pack_w, dim3(E_DIM * D_DIM / 256), dim3(256), 0, stream, w, wsb);
        hipLaunchKernelGGL(router_v4<true>, dim3(grid), dim3(256), 0, stream,
                           x, w, wsb, out, nrows);
    } else {
        hipLaunchKernelGGL(router_v4<false>, dim3(grid), dim3(256), 0, stream,
                           x, w, wsb, out, nrows);
    }
}

// Round 5
// 49.191 us; speedup vs baseline: 1.2537x; 1.2537x over previous
//
#include <hip/hip_runtime.h>
#include <hip/hip_bf16.h>
#include <math.h>

// TopKRouter: x (16384 x 2048) f32 @ gate_w^T (2048 x 64) -> top-2 + softmax.
// Output (f32): [indices as floats (N*2)] ++ [weights (N*2)].
//
// v5: split-bf16 MFMA (3-term, err ~1e-6); x staged via global_load_lds
// (1KB contiguous per instr); per-block K-phase stagger (kills DRAM channel
// camping); depth-2 pipeline with counted vmcnt(8) + raw s_barrier (no
// __syncthreads drain in the main loop); w split inline from L2 (no pack
// kernel). 4 waves split K per chunk; LDS reduce + shfl top-2 epilogue.

constexpr int D_DIM = 2048;
constexpr int E_DIM = 64;
constexpr int BM    = 32;               // rows per block
constexpr int BKC   = 256;              // chunk columns (f32) -> 1KB/row
constexpr int NCH   = D_DIM / BKC;      // 8 chunks
constexpr int LPAD  = 68;               // logits row stride (f32)

typedef __attribute__((ext_vector_type(8))) short s16x8;  // 8 bf16
typedef __attribute__((ext_vector_type(4))) float f32x4;  // MFMA C/D

static __device__ __forceinline__ short f2bf(float f) {
    __hip_bfloat16 h = __float2bfloat16(f);   // RNE
    return *reinterpret_cast<short*>(&h);
}
static __device__ __forceinline__ float b2f(short s) {
    union { unsigned u; float f; } x;
    x.u = ((unsigned)(unsigned short)s) << 16;
    return x.f;
}

__global__ __launch_bounds__(256, 2)
void router_v5(const float* __restrict__ x,
               const float* __restrict__ w,
               float* __restrict__ out,
               int nrows) {
    __shared__ alignas(16) float smem[2][BM * BKC];   // 2 x 32 KB = 64 KB

    const int t    = threadIdx.x;
    const int lane = t & 63;
    const int wv   = t >> 6;            // wave id -> K-slice / staging rows
    const int row0 = blockIdx.x * BM;
    const int l15  = lane & 15;
    const int k8   = lane >> 4;
    const int phase = blockIdx.x & 7;   // K-phase stagger across blocks

    // wave wv stages rows [wv*8, wv*8+8); 1KB contiguous per instruction,
    // global source pre-swizzled, LDS dest linear (rule #21).
    auto stage = [&](int b, int cc) {
        #pragma unroll
        for (int rr = 0; rr < 8; ++rr) {
            const int r = wv * 8 + rr;
            const char* gsrc = (const char*)(x + (size_t)(row0 + r) * D_DIM + cc * BKC);
            const int boff = (lane * 16) ^ ((r & 7) << 4);
            __builtin_amdgcn_global_load_lds(
                (const __attribute__((address_space(1))) void*)(gsrc + boff),
                (__attribute__((address_space(3))) void*)(&smem[b][r * BKC]),
                16, 0, 0);
        }
    };

    f32x4 acc[2][4];
    #pragma unroll
    for (int mf = 0; mf < 2; ++mf)
        #pragma unroll
        for (int nf = 0; nf < 4; ++nf)
            #pragma unroll
            for (int j = 0; j < 4; ++j) acc[mf][nf][j] = 0.f;

    auto compute = [&](int b, int cc) {
        const char* base = (const char*)&smem[b][0];
        #pragma unroll
        for (int s = 0; s < 2; ++s) {                 // 2 K-steps per chunk
            const int kk = cc * BKC + wv * 64 + s * 32 + k8 * 8;
            // ---- B fragments: f32 from L2-resident w, inline hi/lo split ----
            s16x8 bh[4], bl[4];
            #pragma unroll
            for (int nf = 0; nf < 4; ++nf) {
                const float* pw = w + (size_t)(nf * 16 + l15) * D_DIM + kk;
                const float4 w0 = *reinterpret_cast<const float4*>(pw);
                const float4 w1 = *reinterpret_cast<const float4*>(pw + 4);
                const float wvv[8] = {w0.x, w0.y, w0.z, w0.w, w1.x, w1.y, w1.z, w1.w};
                #pragma unroll
                for (int j = 0; j < 8; ++j) {
                    const short h = f2bf(wvv[j]);
                    bh[nf][j] = h;
                    bl[nf][j] = f2bf(wvv[j] - b2f(h));
                }
            }
            // ---- A fragments from LDS (XOR'd read), split hi/lo ----
            const int bc = wv * 256 + s * 128 + k8 * 32;   // byte col in row
            s16x8 ah[2], al[2];
            #pragma unroll
            for (int mf = 0; mf < 2; ++mf) {
                const int r  = mf * 16 + l15;
                const int sw = (r & 7) << 4;
                const char* rp = base + r * (BKC * 4);
                const float4 v0 = *reinterpret_cast<const float4*>(rp + ((bc) ^ sw));
                const float4 v1 = *reinterpret_cast<const float4*>(rp + ((bc + 16) ^ sw));
                const float vv[8] = {v0.x, v0.y, v0.z, v0.w, v1.x, v1.y, v1.z, v1.w};
                #pragma unroll
                for (int j = 0; j < 8; ++j) {
                    const short h = f2bf(vv[j]);
                    ah[mf][j] = h;
                    al[mf][j] = f2bf(vv[j] - b2f(h));
                }
            }
            // ---- 3-term split MFMA ----
            #pragma unroll
            for (int mf = 0; mf < 2; ++mf)
                #pragma unroll
                for (int nf = 0; nf < 4; ++nf) {
                    acc[mf][nf] = __builtin_amdgcn_mfma_f32_16x16x32_bf16(al[mf], bh[nf], acc[mf][nf], 0, 0, 0);
                    acc[mf][nf] = __builtin_amdgcn_mfma_f32_16x16x32_bf16(ah[mf], bl[nf], acc[mf][nf], 0, 0, 0);
                    acc[mf][nf] = __builtin_amdgcn_mfma_f32_16x16x32_bf16(ah[mf], bh[nf], acc[mf][nf], 0, 0, 0);
                }
        }
    };

    // ---- depth-2 pipelined main loop (counted vmcnt, raw barriers) ----
    // Chunk c lives in buf[c&1]; stage of chunk c+2 reuses buf[c&1] after
    // compute(c). vmcnt(8) at iter c drains stage(c) (+ consumed B loads)
    // while keeping stage(c+1)'s 8 loads (always the newest) in flight.
    stage(0, phase);
    stage(1, (phase + 1) & 7);
    #pragma unroll 1
    for (int c = 0; c < NCH; ++c) {
        if (c == NCH - 1) asm volatile("s_waitcnt vmcnt(0)" ::: "memory");
        else              asm volatile("s_waitcnt vmcnt(8)" ::: "memory");
        asm volatile("s_waitcnt lgkmcnt(0)" ::: "memory");
        __builtin_amdgcn_s_barrier();
        asm volatile("" ::: "memory");
        compute(c & 1, (c + phase) & 7);
        if (c + 2 < NCH) {
            asm volatile("s_waitcnt lgkmcnt(0)" ::: "memory");
            __builtin_amdgcn_s_barrier();
            asm volatile("" ::: "memory");
            stage(c & 1, (c + 2 + phase) & 7);
        }
    }
    __syncthreads();

    // ---- partials -> LDS (alias buffers), reduce + top-2 + softmax ----
    float* lgs = &smem[0][0];   // [4][BM][LPAD] = 34.8 KB <= 64 KB
    #pragma unroll
    for (int mf = 0; mf < 2; ++mf)
        #pragma unroll
        for (int nf = 0; nf < 4; ++nf)
            #pragma unroll
            for (int j = 0; j < 4; ++j)
                lgs[((size_t)wv * BM + mf * 16 + k8 * 4 + j) * LPAD + nf * 16 + l15] = acc[mf][nf][j];
    __syncthreads();

    {
        const int row8 = lane >> 3;
        const int seg  = lane & 7;
        const int row  = wv * 8 + row8;
        float sv[8];
        #pragma unroll
        for (int j = 0; j < 8; ++j) sv[j] = 0.f;
        #pragma unroll
        for (int p = 0; p < 4; ++p) {
            const float* rp = &lgs[((size_t)p * BM + row) * LPAD + seg * 8];
            const float4 a  = *reinterpret_cast<const float4*>(rp);
            const float4 bq = *reinterpret_cast<const float4*>(rp + 4);
            sv[0] += a.x;  sv[1] += a.y;  sv[2] += a.z;  sv[3] += a.w;
            sv[4] += bq.x; sv[5] += bq.y; sv[6] += bq.z; sv[7] += bq.w;
        }
        float m1 = sv[0]; int i1 = seg * 8;
        float m2 = -INFINITY; int i2 = 0;
        #pragma unroll
        for (int j = 1; j < 8; ++j) {
            const float v = sv[j]; const int idx = seg * 8 + j;
            if (v > m1)      { m2 = m1; i2 = i1; m1 = v; i1 = idx; }
            else if (v > m2) { m2 = v;  i2 = idx; }
        }
        #pragma unroll
        for (int d = 1; d < 8; d <<= 1) {
            const float M1 = __shfl_xor(m1, d); const int I1 = __shfl_xor(i1, d);
            const float M2 = __shfl_xor(m2, d); const int I2 = __shfl_xor(i2, d);
            const bool sw = (M1 > m1) || (M1 == m1 && I1 < i1);
            const float a1 = sw ? M1 : m1; const int j1 = sw ? I1 : i1;
            const float b1 = sw ? m1 : M1; const int kx = sw ? i1 : I1;
            const float a2 = sw ? M2 : m2; const int j2 = sw ? I2 : i2;
            const bool t2 = (b1 > a2) || (b1 == a2 && kx < j2);
            m1 = a1; i1 = j1;
            m2 = t2 ? b1 : a2; i2 = t2 ? kx : j2;
        }
        if (seg == 0) {
            const float e2v = expf(m2 - m1);
            const float sm  = 1.0f + e2v;
            const long  r   = row0 + row;
            const long  off = (long)nrows * 2;
            out[2 * r + 0]       = (float)i1;
            out[2 * r + 1]       = (float)i2;
            out[off + 2 * r + 0] = 1.0f / sm;
            out[off + 2 * r + 1] = e2v / sm;
        }
    }
}

extern "C" void kernel_launch(void* const* d_in, const int* in_sizes, int n_in,
                              void* d_out, int out_size, void* d_ws, size_t ws_size,
                              hipStream_t stream) {
    const float* x = (const float*)d_in[0];
    const float* w = (const float*)d_in[1];
    float* out = (float*)d_out;
    const int nrows = in_sizes[0] / D_DIM;            // 16384
    const int grid  = nrows / BM;                     // 512
    hipLaunchKernelGGL(router_v5, dim3(grid), dim3(256), 0, stream,
                       x, w, out, nrows);
}